// Round 3
// baseline (555.562 us; speedup 1.0000x reference)
//
#include <hip/hip_runtime.h>
#include <hip/hip_bf16.h>

#define HDIM 128
#define RS 136  // legacy-path LDS row stride in bf16 elements (128 + 8 pad)

typedef __attribute__((ext_vector_type(8))) short short8;
typedef __attribute__((ext_vector_type(4))) float floatv4;

static __device__ __forceinline__ unsigned short f2bf(float f) {
  union { float f; unsigned u; } x; x.f = f;
  unsigned r = x.u + 0x7fffu + ((x.u >> 16) & 1u);  // RNE
  return (unsigned short)(r >> 16);
}
static __device__ __forceinline__ float blo(unsigned u) { return __uint_as_float(u << 16); }
static __device__ __forceinline__ float bhi(unsigned u) { return __uint_as_float(u & 0xffff0000u); }

// ---- async global->LDS DMA (no VGPR round-trip; tracked by vmcnt) ----
static __device__ __forceinline__ void glds16(const void* g, const void* l) {
  __builtin_amdgcn_global_load_lds(
      (const __attribute__((address_space(1))) unsigned int*)(unsigned long long)g,
      (__attribute__((address_space(3))) unsigned int*)(unsigned long long)l, 16, 0, 0);
}
static __device__ __forceinline__ void glds4(const void* g, const void* l) {
  __builtin_amdgcn_global_load_lds(
      (const __attribute__((address_space(1))) unsigned int*)(unsigned long long)g,
      (__attribute__((address_space(3))) unsigned int*)(unsigned long long)l, 4, 0, 0);
}

// Raw barriers: __syncthreads() would drain vmcnt(0) and kill in-flight DMA.
static __device__ __forceinline__ void sync_lds() {   // LDS-producer barrier
  asm volatile("s_waitcnt lgkmcnt(0)" ::: "memory");
  __builtin_amdgcn_s_barrier();
  asm volatile("" ::: "memory");
}
static __device__ __forceinline__ void sync_all() {   // DMA-drain barrier
  asm volatile("s_waitcnt vmcnt(0) lgkmcnt(0)" ::: "memory");
  __builtin_amdgcn_s_barrier();
  asm volatile("" ::: "memory");
}

// Merged prep: block 0 scans seq_len -> offs; blocks 1..128 convert weights to bf16.
__global__ void prep_kernel(const int* __restrict__ seq, int* __restrict__ offs, int B,
                            const float* __restrict__ W1, const float* __restrict__ W2,
                            const float* __restrict__ W3,
                            unsigned short* __restrict__ w1b, unsigned short* __restrict__ w2b,
                            unsigned short* __restrict__ w3b) {
  if (blockIdx.x == 0) {
    __shared__ int part[256];
    int tid = threadIdx.x;
    int chunk = (B + 255) >> 8;
    int beg = tid * chunk, end = min(beg + chunk, B);
    int s = 0;
    for (int i = beg; i < end; ++i) s += seq[i];
    part[tid] = s;
    __syncthreads();
    for (int d = 1; d < 256; d <<= 1) {
      int v = (tid >= d) ? part[tid - d] : 0;
      __syncthreads();
      part[tid] += v;
      __syncthreads();
    }
    int run = (tid == 0) ? 0 : part[tid - 1];
    for (int i = beg; i < end; ++i) { offs[i] = run; run += seq[i]; }
  } else {
    int i = (blockIdx.x - 1) * 256 + threadIdx.x;
    if (i < 16384) { w1b[i] = f2bf(W1[i]); w2b[i] = f2bf(W2[i]); }
    if (i < 32768) { w3b[i] = f2bf(W3[i]); }
  }
}

// Streaming fuse: hidden = max(intra, inter) -> bf16, stored row-SWIZZLED:
// 16-byte group g of token t lands at group position g ^ (t & 7). This makes
// the session kernel's LDS reads (linear DMA dest) bank-conflict-comparable
// to the old padded layout (rule #21: swizzle source + read, never dest).
__global__ __launch_bounds__(256) void fuse_kernel(
    const float* __restrict__ intra, const float* __restrict__ inter,
    unsigned short* __restrict__ hg, long ngroups) {
  long stride = (long)gridDim.x * 256;
  for (long i = (long)blockIdx.x * 256 + threadIdx.x; i < ngroups; i += stride) {
    long t = i >> 4;
    int g = (int)(i & 15);
    const float4* pa = (const float4*)intra + (t << 5) + (g << 1);
    const float4* pb = (const float4*)inter + (t << 5) + (g << 1);
    float4 a0 = pa[0], a1 = pa[1];
    float4 c0 = pb[0], c1 = pb[1];
    union { __hip_bfloat162 b; unsigned u; } p0, p1, p2, p3;
    p0.b = __float22bfloat162_rn(make_float2(fmaxf(a0.x, c0.x), fmaxf(a0.y, c0.y)));
    p1.b = __float22bfloat162_rn(make_float2(fmaxf(a0.z, c0.z), fmaxf(a0.w, c0.w)));
    p2.b = __float22bfloat162_rn(make_float2(fmaxf(a1.x, c1.x), fmaxf(a1.y, c1.y)));
    p3.b = __float22bfloat162_rn(make_float2(fmaxf(a1.z, c1.z), fmaxf(a1.w, c1.w)));
    uint4 o; o.x = p0.u; o.y = p1.u; o.z = p2.u; o.w = p3.u;
    int gs = g ^ (int)(t & 7);
    *(uint4*)(hg + t * HDIM + (gs << 3)) = o;
  }
}

// DMA one session's bf16 tile (n rows x 256 B) into LDS, linear dest.
static __device__ __forceinline__ void dma_tile(
    const unsigned short* __restrict__ hg, int start, int n,
    unsigned short* dst, int wid, int lane) {
  const char* g = (const char*)(hg + (size_t)start * HDIM);
  char* l = (char*)dst;
  int nf = n >> 2;                       // 1-KB chunks = 4 rows
  for (int c = wid; c < nf; c += 4) {
    int off = c << 10;
    glds16(g + off + (lane << 4), l + off);
  }
  if (wid == 0) {                        // tail rows (<=3), 256 B each
    for (int r = nf << 2; r < n; ++r) {
      int off = r << 8;
      glds4(g + off + (lane << 2), l + off);
    }
  }
}

// Zero rows [n, 64): makes garbage-row contributions exactly 0 in s_g
// (alpha for rows >= n can then be anything finite; 0 * finite = 0).
static __device__ __forceinline__ void zero_tail(unsigned short* dst, int n, int tid) {
  int cnt = (64 - n) << 4;               // 16-B units
  uint4 z; z.x = 0u; z.y = 0u; z.z = 0u; z.w = 0u;
  for (int i = tid; i < cnt; i += 256)
    *(uint4*)(dst + (n << 7) + (i << 3)) = z;
}

// 3 blocks/CU (LDS 36 KB, VGPR-capped by launch_bounds). DMA double-buffers
// bf16 tiles; w2f/w3f register-resident; per-session W1 loads placed BEFORE
// the DMA issue (a VMEM load younger than the DMA would force its compiler
// waitcnt to drain the whole DMA FIFO — vmcnt is in-order).
__global__ __launch_bounds__(256, 3) void session_kernel(
    const unsigned short* __restrict__ hg,
    const unsigned short* __restrict__ w1b, const float* __restrict__ b1,
    const unsigned short* __restrict__ w2b, const float* __restrict__ b2,
    const float* __restrict__ qw, const float* __restrict__ qb,
    const unsigned short* __restrict__ w3b, const float* __restrict__ b3,
    const int* __restrict__ seq, const int* __restrict__ offs,
    float* __restrict__ out, int B) {
  __shared__ __align__(16) unsigned short hb[2][64 * HDIM];  // 2 x 16 KB
  __shared__ __align__(16) unsigned short vnb[HDIM];
  __shared__ __align__(16) unsigned short sgb[HDIM];
  __shared__ float alphaAcc[64];
  __shared__ __align__(16) float sgpart[4][HDIM];

  const int tid = threadIdx.x;
  const int lane = tid & 63, wid = tid >> 6;
  const int quad = lane >> 4, lcol = lane & 15;
  const int nbase = wid << 5;
  const int n0 = nbase + lcol, n1 = n0 + 16;
  const int G = gridDim.x;

  const float qb0 = qb[0];
  const float bb0 = b1[n0] + b2[n0], bb1 = b1[n1] + b2[n1];
  const float q0 = qw[n0], q1 = qw[n1];
  const float b30 = b3[n0], b31 = b3[n1];

  // Resident W2 (32 VGPR) + W3 (64 VGPR) fragments: keeps phases 5-7 VMEM-free.
  short8 w2f[2][4], w3f[2][8];
  #pragma unroll
  for (int kt = 0; kt < 4; ++kt) {
    w2f[0][kt] = *(const short8*)(w2b + n0 * HDIM + (kt << 5) + (quad << 3));
    w2f[1][kt] = *(const short8*)(w2b + n1 * HDIM + (kt << 5) + (quad << 3));
  }
  #pragma unroll
  for (int kt = 0; kt < 8; ++kt) {
    w3f[0][kt] = *(const short8*)(w3b + n0 * 256 + (kt << 5) + (quad << 3));
    w3f[1][kt] = *(const short8*)(w3b + n1 * 256 + (kt << 5) + (quad << 3));
  }

  // Prologue: first session's DMA into buffer 0.
  int n_cur, st_cur;
  {
    int s0 = blockIdx.x;
    n_cur = seq[s0]; if (n_cur > 64) n_cur = 64;  // dataset: L == 50
    st_cur = offs[s0];
    dma_tile(hg, st_cur, n_cur, hb[0], wid, lane);
    zero_tail(hb[0], n_cur, tid);
  }
  int cur = 0;

  for (int s = blockIdx.x; s < B; s += G) {
    const int sn = s + G;
    int n_nxt = 0, st_nxt = 0;
    if (sn < B) { n_nxt = seq[sn]; if (n_nxt > 64) n_nxt = 64; st_nxt = offs[sn]; }

    // v_n: direct 256-B global read of the last valid row (bf16, swizzled).
    unsigned vnr = 0;
    {
      int tl = st_cur + n_cur - 1; if (tl < 0) tl = 0;
      if (tid < 64) {
        int gsw = (tid >> 2) ^ (tl & 7);
        vnr = *(const unsigned*)((const char*)hg + (size_t)tl * 256 +
                                 (gsw << 4) + ((tid & 3) << 2));
      }
    }

    sync_all();  // drains current tile's DMA + vnr (the ONE intended vmcnt(0))

    if (tid < 64) { *(unsigned*)&vnb[tid << 1] = vnr; alphaAcc[tid] = qb0; }
    sync_lds();  // B1: vnb + alphaAcc visible

    // Phase 4 (BEFORE DMA issue): c[n] = W1 @ v_n + b1 + b2. The only
    // per-session VMEM loads; older than the upcoming DMA -> cheap waits.
    float c0, c1;
    {
      floatv4 p0 = {0.f, 0.f, 0.f, 0.f}, p1 = {0.f, 0.f, 0.f, 0.f};
      #pragma unroll
      for (int kt = 0; kt < 4; ++kt) {
        short8 af = *(const short8*)&vnb[(kt << 5) + (quad << 3)];
        short8 bf0 = *(const short8*)(w1b + n0 * HDIM + (kt << 5) + (quad << 3));
        short8 bf1 = *(const short8*)(w1b + n1 * HDIM + (kt << 5) + (quad << 3));
        p0 = __builtin_amdgcn_mfma_f32_16x16x32_bf16(af, bf0, p0, 0, 0, 0);
        p1 = __builtin_amdgcn_mfma_f32_16x16x32_bf16(af, bf1, p1, 0, 0, 0);
      }
      c0 = p0[0] + bb0;
      c1 = p1[0] + bb1;
    }

    // Issue NEXT session's DMA; streams under phases 5-7 (all VMEM-free).
    if (sn < B) {
      dma_tile(hg, st_nxt, n_nxt, hb[cur ^ 1], wid, lane);
      zero_tail(hb[cur ^ 1], n_nxt, tid);
    }
    asm volatile("" ::: "memory");  // pin issue point

    // Phase 5: D = hidden @ W2^T + c; fused sigmoid + q-dot -> alphaAcc.
    const unsigned short* hc = hb[cur];
    const int st7 = st_cur & 7;
    const int p5 = (st7 + lcol) & 7;     // read-side swizzle parity (row = lcol mod 8)
    #pragma unroll
    for (int mt = 0; mt < 4; ++mt) {
      floatv4 a0 = {c0, c0, c0, c0}, a1 = {c1, c1, c1, c1};
      const unsigned short* rbase = hc + ((mt << 4) + lcol) * HDIM;
      #pragma unroll
      for (int kt = 0; kt < 4; ++kt) {
        int gidx = ((kt << 2) | quad) ^ p5;
        short8 af = *(const short8*)(rbase + (gidx << 3));
        a0 = __builtin_amdgcn_mfma_f32_16x16x32_bf16(af, w2f[0][kt], a0, 0, 0, 0);
        a1 = __builtin_amdgcn_mfma_f32_16x16x32_bf16(af, w2f[1][kt], a1, 0, 0, 0);
      }
      #pragma unroll
      for (int r = 0; r < 4; ++r) {
        float v = q0 * __builtin_amdgcn_rcpf(1.f + __expf(-a0[r]))
                + q1 * __builtin_amdgcn_rcpf(1.f + __expf(-a1[r]));
        v += __shfl_xor(v, 1, 64);
        v += __shfl_xor(v, 2, 64);
        v += __shfl_xor(v, 4, 64);
        v += __shfl_xor(v, 8, 64);
        if (lcol == 0) atomicAdd(&alphaAcc[(mt << 4) + (quad << 2) + r], v);
      }
    }
    sync_lds();  // B2: alphaAcc complete

    // Phase 6: s_g partials (alpha-weighted sum over tokens).
    {
      int jg = tid & 15, ts = tid >> 4;
      const int p6 = (st7 + ts) & 7;
      float ac[8];
      #pragma unroll
      for (int e = 0; e < 8; ++e) ac[e] = 0.f;
      #pragma unroll
      for (int tt = 0; tt < 4; ++tt) {
        int t = (tt << 4) + ts;
        float al = alphaAcc[t];
        uint4 u = *(const uint4*)(hc + (t << 7) + ((jg ^ p6) << 3));
        ac[0] += al * blo(u.x); ac[1] += al * bhi(u.x);
        ac[2] += al * blo(u.y); ac[3] += al * bhi(u.y);
        ac[4] += al * blo(u.z); ac[5] += al * bhi(u.z);
        ac[6] += al * blo(u.w); ac[7] += al * bhi(u.w);
      }
      #pragma unroll
      for (int e = 0; e < 8; ++e) {
        ac[e] += __shfl_xor(ac[e], 16, 64);
        ac[e] += __shfl_xor(ac[e], 32, 64);
      }
      if (quad == 0) {
        float4 s0v; s0v.x = ac[0]; s0v.y = ac[1]; s0v.z = ac[2]; s0v.w = ac[3];
        float4 s1v; s1v.x = ac[4]; s1v.y = ac[5]; s1v.z = ac[6]; s1v.w = ac[7];
        *(float4*)&sgpart[wid][(jg << 3)] = s0v;
        *(float4*)&sgpart[wid][(jg << 3) + 4] = s1v;
      }
    }
    sync_lds();  // B3
    if (tid < HDIM) {
      float sv = sgpart[0][tid] + sgpart[1][tid] + sgpart[2][tid] + sgpart[3][tid];
      sgb[tid] = f2bf(sv);
    }
    sync_lds();  // B4

    // Phase 7: h_s = [v_n, s_g] @ W3^T + b3 (weights resident -> no VMEM).
    {
      floatv4 o0 = {0.f, 0.f, 0.f, 0.f}, o1 = {0.f, 0.f, 0.f, 0.f};
      #pragma unroll
      for (int kt = 0; kt < 8; ++kt) {
        const unsigned short* src = (kt < 4) ? &vnb[kt << 5] : &sgb[(kt - 4) << 5];
        short8 af = *(const short8*)(src + (quad << 3));
        o0 = __builtin_amdgcn_mfma_f32_16x16x32_bf16(af, w3f[0][kt], o0, 0, 0, 0);
        o1 = __builtin_amdgcn_mfma_f32_16x16x32_bf16(af, w3f[1][kt], o1, 0, 0, 0);
      }
      if (quad == 0) {
        out[(size_t)s * HDIM + n0] = o0[0] + b30;
        out[(size_t)s * HDIM + n1] = o1[0] + b31;
      }
    }

    cur ^= 1;
    n_cur = n_nxt;
    st_cur = st_nxt;
  }
}

// ================= legacy fallback (round-2 verified path) =================
static __device__ __forceinline__ void dma_session_fb(
    const float* __restrict__ intra, const float* __restrict__ inter,
    int start, int n, float* rawA, float* rawB, int wid, int lane) {
  const char* ga = (const char*)(intra + (size_t)start * HDIM);
  const char* gb = (const char*)(inter + (size_t)start * HDIM);
  char* la = (char*)rawA;
  char* lb = (char*)rawB;
  int nfull = n >> 1;
  for (int i = wid; i < nfull; i += 4) {
    int off = i << 10;
    glds16(ga + off + (lane << 4), la + off);
    glds16(gb + off + (lane << 4), lb + off);
  }
  if ((n & 1) && wid == 0) {
    int off = (n - 1) << 9;
    glds4(ga + off + (lane << 2), la + off);
    glds4(ga + off + 256 + (lane << 2), la + off + 256);
    glds4(gb + off + (lane << 2), lb + off);
    glds4(gb + off + 256 + (lane << 2), lb + off + 256);
  }
}

__global__ __launch_bounds__(256, 1) void session_kernel_fb(
    const float* __restrict__ intra, const float* __restrict__ inter,
    const unsigned short* __restrict__ w1b, const float* __restrict__ b1,
    const unsigned short* __restrict__ w2b, const float* __restrict__ b2,
    const float* __restrict__ qw, const float* __restrict__ qb,
    const unsigned short* __restrict__ w3b, const float* __restrict__ b3,
    const int* __restrict__ seq, const int* __restrict__ offs,
    float* __restrict__ out, int B) {
  __shared__ float rawA[2][64 * HDIM];
  __shared__ float rawB[2][64 * HDIM];
  __shared__ unsigned short hbf[64 * RS];
  __shared__ unsigned short vnb[HDIM];
  __shared__ unsigned short sgb[HDIM];
  __shared__ float alphaAcc[64];
  __shared__ float sgpart[4][HDIM];

  const int tid = threadIdx.x;
  const int lane = tid & 63, wid = tid >> 6;
  const int quad = lane >> 4, lcol = lane & 15;
  const int nbase = wid << 5;
  const int n0 = nbase + lcol, n1 = n0 + 16;
  const int G = gridDim.x;

  const float qb0 = qb[0];
  const float bb0 = b1[n0] + b2[n0], bb1 = b1[n1] + b2[n1];
  const float q0 = qw[n0], q1 = qw[n1];
  const float b30 = b3[n0], b31 = b3[n1];

  short8 w1f[2][4], w2f[2][4], w3f[2][8];
  #pragma unroll
  for (int kt = 0; kt < 4; ++kt) {
    w1f[0][kt] = *(const short8*)(w1b + n0 * HDIM + (kt << 5) + (quad << 3));
    w1f[1][kt] = *(const short8*)(w1b + n1 * HDIM + (kt << 5) + (quad << 3));
    w2f[0][kt] = *(const short8*)(w2b + n0 * HDIM + (kt << 5) + (quad << 3));
    w2f[1][kt] = *(const short8*)(w2b + n1 * HDIM + (kt << 5) + (quad << 3));
  }
  #pragma unroll
  for (int kt = 0; kt < 8; ++kt) {
    w3f[0][kt] = *(const short8*)(w3b + n0 * 256 + (kt << 5) + (quad << 3));
    w3f[1][kt] = *(const short8*)(w3b + n1 * 256 + (kt << 5) + (quad << 3));
  }

  int n_cur;
  {
    int s0 = blockIdx.x;
    n_cur = seq[s0]; if (n_cur > 64) n_cur = 64;
    dma_session_fb(intra, inter, offs[s0], n_cur, rawA[0], rawB[0], wid, lane);
  }
  int cur = 0;

  for (int s = blockIdx.x; s < B; s += G) {
    const int sn = s + G;
    int n_nxt = 0, st_nxt = 0;
    if (sn < B) { n_nxt = seq[sn]; if (n_nxt > 64) n_nxt = 64; st_nxt = offs[sn]; }

    sync_all();
    if (sn < B)
      dma_session_fb(intra, inter, st_nxt, n_nxt, rawA[cur ^ 1], rawB[cur ^ 1], wid, lane);
    asm volatile("" ::: "memory");

    {
      const float4* a4 = (const float4*)rawA[cur];
      const float4* c4 = (const float4*)rawB[cur];
      const int lastrow = (n_cur > 0) ? (n_cur - 1) : 0;
      #pragma unroll
      for (int it = 0; it < 8; ++it) {
        int idx = (it << 8) + tid;
        int t = idx >> 5, j4 = idx & 31;
        float4 r; r.x = 0.f; r.y = 0.f; r.z = 0.f; r.w = 0.f;
        if (t < n_cur) {
          float4 a = a4[idx], c = c4[idx];
          r.x = fmaxf(a.x, c.x); r.y = fmaxf(a.y, c.y);
          r.z = fmaxf(a.z, c.z); r.w = fmaxf(a.w, c.w);
        }
        union { __hip_bfloat162 b; unsigned u; } p01, p23;
        p01.b = __float22bfloat162_rn(make_float2(r.x, r.y));
        p23.b = __float22bfloat162_rn(make_float2(r.z, r.w));
        uint2 st; st.x = p01.u; st.y = p23.u;
        *(uint2*)&hbf[t * RS + (j4 << 2)] = st;
        if (t == lastrow) *(uint2*)&vnb[j4 << 2] = st;
      }
      if (tid < 64) alphaAcc[tid] = qb0;
    }
    sync_lds();

    float c0, c1;
    {
      floatv4 p0 = {0.f, 0.f, 0.f, 0.f}, p1 = {0.f, 0.f, 0.f, 0.f};
      #pragma unroll
      for (int kt = 0; kt < 4; ++kt) {
        short8 af = *(const short8*)&vnb[(kt << 5) + (quad << 3)];
        p0 = __builtin_amdgcn_mfma_f32_16x16x32_bf16(af, w1f[0][kt], p0, 0, 0, 0);
        p1 = __builtin_amdgcn_mfma_f32_16x16x32_bf16(af, w1f[1][kt], p1, 0, 0, 0);
      }
      c0 = p0[0] + bb0;
      c1 = p1[0] + bb1;
    }

    #pragma unroll
    for (int mt = 0; mt < 4; ++mt) {
      floatv4 a0 = {c0, c0, c0, c0}, a1 = {c1, c1, c1, c1};
      const unsigned short* arow = &hbf[((mt << 4) + lcol) * RS + (quad << 3)];
      #pragma unroll
      for (int kt = 0; kt < 4; ++kt) {
        short8 af = *(const short8*)(arow + (kt << 5));
        a0 = __builtin_amdgcn_mfma_f32_16x16x32_bf16(af, w2f[0][kt], a0, 0, 0, 0);
        a1 = __builtin_amdgcn_mfma_f32_16x16x32_bf16(af, w2f[1][kt], a1, 0, 0, 0);
      }
      #pragma unroll
      for (int r = 0; r < 4; ++r) {
        float v = q0 * __builtin_amdgcn_rcpf(1.f + __expf(-a0[r]))
                + q1 * __builtin_amdgcn_rcpf(1.f + __expf(-a1[r]));
        v += __shfl_xor(v, 1, 64);
        v += __shfl_xor(v, 2, 64);
        v += __shfl_xor(v, 4, 64);
        v += __shfl_xor(v, 8, 64);
        if (lcol == 0) atomicAdd(&alphaAcc[(mt << 4) + (quad << 2) + r], v);
      }
    }
    sync_lds();

    {
      int jg = tid & 15, ts = tid >> 4;
      float ac[8];
      #pragma unroll
      for (int e = 0; e < 8; ++e) ac[e] = 0.f;
      #pragma unroll
      for (int tt = 0; tt < 4; ++tt) {
        int t = (tt << 4) + ts;
        float al = alphaAcc[t];
        uint4 u = *(const uint4*)&hbf[t * RS + (jg << 3)];
        ac[0] += al * blo(u.x); ac[1] += al * bhi(u.x);
        ac[2] += al * blo(u.y); ac[3] += al * bhi(u.y);
        ac[4] += al * blo(u.z); ac[5] += al * bhi(u.z);
        ac[6] += al * blo(u.w); ac[7] += al * bhi(u.w);
      }
      #pragma unroll
      for (int e = 0; e < 8; ++e) {
        ac[e] += __shfl_xor(ac[e], 16, 64);
        ac[e] += __shfl_xor(ac[e], 32, 64);
      }
      if (quad == 0) {
        float4 s0v; s0v.x = ac[0]; s0v.y = ac[1]; s0v.z = ac[2]; s0v.w = ac[3];
        float4 s1v; s1v.x = ac[4]; s1v.y = ac[5]; s1v.z = ac[6]; s1v.w = ac[7];
        *(float4*)&sgpart[wid][(jg << 3)] = s0v;
        *(float4*)&sgpart[wid][(jg << 3) + 4] = s1v;
      }
    }
    sync_lds();
    if (tid < HDIM) {
      float sv = sgpart[0][tid] + sgpart[1][tid] + sgpart[2][tid] + sgpart[3][tid];
      sgb[tid] = f2bf(sv);
    }
    sync_lds();

    {
      floatv4 o0 = {0.f, 0.f, 0.f, 0.f}, o1 = {0.f, 0.f, 0.f, 0.f};
      #pragma unroll
      for (int kt = 0; kt < 8; ++kt) {
        const unsigned short* src = (kt < 4) ? &vnb[kt << 5] : &sgb[(kt - 4) << 5];
        short8 af = *(const short8*)(src + (quad << 3));
        o0 = __builtin_amdgcn_mfma_f32_16x16x32_bf16(af, w3f[0][kt], o0, 0, 0, 0);
        o1 = __builtin_amdgcn_mfma_f32_16x16x32_bf16(af, w3f[1][kt], o1, 0, 0, 0);
      }
      if (quad == 0) {
        out[(size_t)s * HDIM + n0] = o0[0] + b30;
        out[(size_t)s * HDIM + n1] = o1[0] + b31;
      }
    }

    cur ^= 1;
    n_cur = n_nxt;
  }
}

extern "C" void kernel_launch(void* const* d_in, const int* in_sizes, int n_in,
                              void* d_out, int out_size, void* d_ws, size_t ws_size,
                              hipStream_t stream) {
  const float* intra = (const float*)d_in[0];
  const float* inter = (const float*)d_in[1];
  const float* W1 = (const float*)d_in[2];
  const float* b1 = (const float*)d_in[3];
  const float* W2 = (const float*)d_in[4];
  const float* b2 = (const float*)d_in[5];
  const float* qw = (const float*)d_in[6];
  const float* qb = (const float*)d_in[7];
  const float* W3 = (const float*)d_in[8];
  const float* b3 = (const float*)d_in[9];
  const int* seq = (const int*)d_in[10];
  const int B = in_sizes[10];
  const long T = (long)in_sizes[0] / HDIM;
  float* out = (float*)d_out;

  char* ws = (char*)d_ws;
  size_t o1 = (((size_t)B * 4) + 255) & ~(size_t)255;
  int* offs = (int*)ws;
  unsigned short* w1b = (unsigned short*)(ws + o1);            // 32 KB
  unsigned short* w2b = (unsigned short*)(ws + o1 + 32768);    // 32 KB
  unsigned short* w3b = (unsigned short*)(ws + o1 + 65536);    // 64 KB
  unsigned short* hg  = (unsigned short*)(ws + o1 + 131072);   // T*256 B

  size_t needed = o1 + 131072 + (size_t)T * 256;

  hipLaunchKernelGGL(prep_kernel, dim3(129), dim3(256), 0, stream,
                     seq, offs, B, W1, W2, W3, w1b, w2b, w3b);

  if (ws_size >= needed) {
    hipLaunchKernelGGL(fuse_kernel, dim3(2048), dim3(256), 0, stream,
                       intra, inter, hg, T * 16);
    int nblk = B < 768 ? B : 768;  // 3 blocks/CU
    hipLaunchKernelGGL(session_kernel, dim3(nblk), dim3(256), 0, stream,
                       hg, w1b, b1, w2b, b2, qw, qb, w3b, b3, seq, offs, out, B);
  } else {
    int nblk = B < 256 ? B : 256;
    hipLaunchKernelGGL(session_kernel_fb, dim3(nblk), dim3(256), 0, stream,
                       intra, inter, w1b, b1, w2b, b2, qw, qb, w3b, b3, seq, offs, out, B);
  }
}